// Round 13
// baseline (61.827 us; speedup 1.0000x reference)
//
#include <hip/hip_runtime.h>

// L=32768, N=32, E=H=1, BS=256 -> 4096 rank-1 softmax problems:
//   out_i = sum_j 2^(a'_i k_j) v_j / sum_j 2^(a'_i k_j),  a' = (wq q + bq) log2e.
//
// R13 = R12 with the missing NBLK macro restored (compile fix; theory untested).
// The wall across R1-R11 is the TRANS pipe: 4096 v_exp_f32 wave-insts per
// SIMD x ~25cy = 102k cy = 42us, invariant under every memory/VALU change.
// Reduce exp COUNT ~2x by pairing j's with close k (counting semi-sort):
//   p0+p1       = E * 2cosh(b),                E = 2^(a'*s), b = a'*d*ln2
//   p0 v0+p1 v1 = E * [(v0+v1) cosh + (v1-v0) sinh]
// cosh/sinh -> small polys valid for |b|<=0.5; pairs failing the bound
// take a 2-exp fallback (exact R11 math), so sort quality affects ONLY speed.
// Sums over j are permutation-invariant -> semi-sort cannot break correctness.
// No max-subtraction (|a's|<=~31, f32-safe; validated R5-R11).

#define LL    32768
#define NN    32
#define BSZ   256
#define NBLK  (LL / BSZ)
#define NPAIR (BSZ / 2)
#define LOG2E 1.4426950408889634f
#define LN2   0.6931471805599453f
#define BMAX  0.5f

typedef float v2f __attribute__((ext_vector_type(2)));

__global__ __launch_bounds__(256) void BlockCrossAttn_kernel(
    const float* __restrict__ q_in, const float* __restrict__ k_in,
    const float* __restrict__ v_in,
    const float* __restrict__ ipw,  const float* __restrict__ ipb,
    const float* __restrict__ opw,  const float* __restrict__ opb,
    float* __restrict__ out)
{
    const int wid  = threadIdx.x >> 6;       // wave 0..3: one problem each
    const int lane = threadIdx.x & 63;
    const int prob = blockIdx.x * 4 + wid;   // 0..4095
    const int blk  = prob >> 5;
    const int n    = prob & 31;

    const float wq = ipw[0], wk = ipw[1], wv = ipw[2];
    const float bq = ipb[0], bk = ipb[1], bv = ipb[2];

    __shared__ alignas(16) float2 skv[4][BSZ];     // semi-sorted (k, v)
    __shared__ alignas(16) float4 drv[4][NPAIR];   // (s, dn, vsh, vd)
    __shared__ int hist[4][128];

    // ---- prologue: gather + project (k,v stay in regs for the scatter) ----
    float a[4], kr[4], vr[4];
    #pragma unroll
    for (int r = 0; r < 4; ++r) {
        const int gi = (blk * BSZ + r * 64 + lane) * NN + n;
        a[r]  = fmaf(q_in[gi], wq, bq) * LOG2E;
        kr[r] = fmaf(k_in[gi], wk, bk);
        vr[r] = fmaf(v_in[gi], wv, bv);
    }

    // wave reductions: max|a|, kmin, kmax
    float am  = fmaxf(fmaxf(fabsf(a[0]), fabsf(a[1])), fmaxf(fabsf(a[2]), fabsf(a[3])));
    float kmn = fminf(fminf(kr[0], kr[1]), fminf(kr[2], kr[3]));
    float kmx = fmaxf(fmaxf(kr[0], kr[1]), fmaxf(kr[2], kr[3]));
    #pragma unroll
    for (int off = 32; off >= 1; off >>= 1) {
        am  = fmaxf(am,  __shfl_xor(am,  off));
        kmn = fminf(kmn, __shfl_xor(kmn, off));
        kmx = fmaxf(kmx, __shfl_xor(kmx, off));
    }

    // ---- counting semi-sort by 7-bit quantized k ----
    hist[wid][lane]      = 0;
    hist[wid][lane + 64] = 0;
    __syncthreads();

    const float rng  = kmx - kmn;
    const float binv = (rng > 0.f) ? (127.99f / rng) : 0.f;
    int bin[4];
    #pragma unroll
    for (int r = 0; r < 4; ++r) {
        int b = (int)((kr[r] - kmn) * binv);
        bin[r] = (b < 0) ? 0 : ((b > 127) ? 127 : b);
        atomicAdd(&hist[wid][bin[r]], 1);   // per-wave LDS atomics: lane-ordered
    }
    __syncthreads();

    // exclusive scan of 128 bins (two 64-wide shfl scans)
    const int c0 = hist[wid][lane];
    const int c1 = hist[wid][lane + 64];
    int i0 = c0, i1 = c1;
    #pragma unroll
    for (int off = 1; off <= 32; off <<= 1) {
        const int t0 = __shfl_up(i0, off);
        const int t1 = __shfl_up(i1, off);
        if (lane >= off) { i0 += t0; i1 += t1; }
    }
    const int tot0 = __shfl(i0, 63);
    hist[wid][lane]      = i0 - c0;
    hist[wid][lane + 64] = i1 - c1 + tot0;
    __syncthreads();

    // scatter (bijective: scan base + per-wave atomic rank)
    #pragma unroll
    for (int r = 0; r < 4; ++r) {
        const int slot = atomicAdd(&hist[wid][bin[r]], 1);
        skv[wid][slot] = make_float2(kr[r], vr[r]);
    }
    __syncthreads();

    // ---- pair-derived values: s, dn = (k1-k0)*ln2/2, vsh = (v0+v1)/2, vd ----
    #pragma unroll
    for (int m = 0; m < 2; ++m) {
        const int pp = m * 64 + lane;
        const float2 e0 = skv[wid][2 * pp];
        const float2 e1 = skv[wid][2 * pp + 1];
        drv[wid][pp] = make_float4(0.5f * (e0.x + e1.x),
                                   0.5f * LN2 * (e1.x - e0.x),
                                   0.5f * (e0.y + e1.y),
                                   e1.y - e0.y);
    }
    __syncthreads();

    // ---- main loop over 128 pairs ----
    const v2f a01 = {a[0], a[1]};
    const v2f a23 = {a[2], a[3]};
    const v2f one = {1.f, 1.f}, two = {2.f, 2.f};
    const v2f K12 = {1.f/12.f, 1.f/12.f}, K360 = {1.f/360.f, 1.f/360.f};
    const v2f K6  = {1.f/6.f, 1.f/6.f},  K120 = {1.f/120.f, 1.f/120.f};

    v2f den01 = {0.f, 0.f}, den23 = {0.f, 0.f};
    v2f num01 = {0.f, 0.f}, num23 = {0.f, 0.f};

    const float4* __restrict__ D4 = drv[wid];
    const float4* __restrict__ R4 = (const float4*)skv[wid];  // (k0,v0,k1,v1)

    #pragma unroll 2
    for (int pp = 0; pp < NPAIR; ++pp) {
        const float4 D = D4[pp];                 // uniform ds_read_b128
        if (am * fabsf(D.y) <= BMAX) {
            const v2f ss = {D.x, D.x}, dd = {D.y, D.y};
            const v2f vs = {D.z, D.z}, vd = {D.w, D.w};
            {   // rows 0,1
                const v2f as = a01 * ss;
                v2f E; E.x = __builtin_amdgcn_exp2f(as.x);
                       E.y = __builtin_amdgcn_exp2f(as.y);
                const v2f b  = a01 * dd;
                const v2f x  = b * b;
                const v2f C  = __builtin_elementwise_fma(x, __builtin_elementwise_fma(x, K360, K12), one);
                const v2f C2 = __builtin_elementwise_fma(x, C, two);          // 2cosh
                const v2f S  = __builtin_elementwise_fma(x, __builtin_elementwise_fma(x, K120, K6), one); // sinh/b
                const v2f bv = b * vd;
                v2f t = vs * C2;
                t = __builtin_elementwise_fma(bv, S, t);
                den01 = __builtin_elementwise_fma(E, C2, den01);
                num01 = __builtin_elementwise_fma(E, t,  num01);
            }
            {   // rows 2,3
                const v2f as = a23 * ss;
                v2f E; E.x = __builtin_amdgcn_exp2f(as.x);
                       E.y = __builtin_amdgcn_exp2f(as.y);
                const v2f b  = a23 * dd;
                const v2f x  = b * b;
                const v2f C  = __builtin_elementwise_fma(x, __builtin_elementwise_fma(x, K360, K12), one);
                const v2f C2 = __builtin_elementwise_fma(x, C, two);
                const v2f S  = __builtin_elementwise_fma(x, __builtin_elementwise_fma(x, K120, K6), one);
                const v2f bv = b * vd;
                v2f t = vs * C2;
                t = __builtin_elementwise_fma(bv, S, t);
                den23 = __builtin_elementwise_fma(E, C2, den23);
                num23 = __builtin_elementwise_fma(E, t,  num23);
            }
        } else {
            // fallback: two direct exps per row (exact R11 math)
            const float4 R = R4[pp];
            const v2f k0 = {R.x, R.x}, v0 = {R.y, R.y};
            const v2f k1 = {R.z, R.z}, v1 = {R.w, R.w};
            {
                const v2f g0 = a01 * k0, g1 = a01 * k1;
                v2f P0, P1;
                P0.x = __builtin_amdgcn_exp2f(g0.x); P0.y = __builtin_amdgcn_exp2f(g0.y);
                P1.x = __builtin_amdgcn_exp2f(g1.x); P1.y = __builtin_amdgcn_exp2f(g1.y);
                den01 += P0; den01 += P1;
                num01 = __builtin_elementwise_fma(P0, v0, num01);
                num01 = __builtin_elementwise_fma(P1, v1, num01);
            }
            {
                const v2f g0 = a23 * k0, g1 = a23 * k1;
                v2f P0, P1;
                P0.x = __builtin_amdgcn_exp2f(g0.x); P0.y = __builtin_amdgcn_exp2f(g0.y);
                P1.x = __builtin_amdgcn_exp2f(g1.x); P1.y = __builtin_amdgcn_exp2f(g1.y);
                den23 += P0; den23 += P1;
                num23 = __builtin_elementwise_fma(P0, v0, num23);
                num23 = __builtin_elementwise_fma(P1, v1, num23);
            }
        }
    }

    const float wo = opw[0], bo = opb[0];
    const int rbase = blk * BSZ;
    out[(size_t)(rbase +   0 + lane) * NN + n] = fmaf(num01.x / den01.x, wo, bo);
    out[(size_t)(rbase +  64 + lane) * NN + n] = fmaf(num01.y / den01.y, wo, bo);
    out[(size_t)(rbase + 128 + lane) * NN + n] = fmaf(num23.x / den23.x, wo, bo);
    out[(size_t)(rbase + 192 + lane) * NN + n] = fmaf(num23.y / den23.y, wo, bo);
}

extern "C" void kernel_launch(void* const* d_in, const int* in_sizes, int n_in,
                              void* d_out, int out_size, void* d_ws, size_t ws_size,
                              hipStream_t stream) {
    const float* q   = (const float*)d_in[0];
    const float* k   = (const float*)d_in[1];
    const float* v   = (const float*)d_in[2];
    const float* ipw = (const float*)d_in[3];
    const float* ipb = (const float*)d_in[4];
    const float* opw = (const float*)d_in[5];
    const float* opb = (const float*)d_in[6];
    float* out = (float*)d_out;

    dim3 grid(NBLK * NN / 4);   // 1024 WGs x 4 waves; one problem per wave
    dim3 block(256);
    BlockCrossAttn_kernel<<<grid, block, 0, stream>>>(q, k, v, ipw, ipb, opw, opb, out);
}

// Round 15
// 51.738 us; speedup vs baseline: 1.1950x; 1.1950x over previous
//
#include <hip/hip_runtime.h>

// L=32768, N=32, E=H=1, BS=256 -> 4096 rank-1 softmax problems:
//   out_i = sum_j 2^(a'_i k_j) v_j / sum_j 2^(a'_i k_j),  a' = (wq q + bq) log2e.
// No max-subtraction (|a'k| <= ~39 log2 units, f32-safe, scale-invariant;
// validated R5-R13).
//
// R15 = R14 with the inner-loop bound fixed (was BSZ/4: summed only half the
// keys -> absmax 0.2; now BSZ/2 covers all 128 float4 chunks = 256 j).
//   Kernel P: projection + transpose -> ws = A(=a*log2e),K,V as [N][L] planes.
//   Kernel A: one WG per (blk,n); coalesced loads; (k,v) float2-interleaved in
//             LDS; per 2 j: 1 v_pk_mul + 2 v_exp + 1 v_pk_add + 1 v_pk_fma.

#define LL    32768
#define NN    32
#define BSZ   256
#define NBLK  (LL / BSZ)
#define LOG2E 1.4426950408889634f

typedef float v2f __attribute__((ext_vector_type(2)));

// ---------------- Kernel P: projection + transpose (verified) ----------
__global__ __launch_bounds__(256) void proj_transpose_kernel(
    const float* __restrict__ q_in, const float* __restrict__ k_in,
    const float* __restrict__ v_in,
    const float* __restrict__ ipw,  const float* __restrict__ ipb,
    float* __restrict__ ws)
{
    __shared__ float sa[32][33], sk[32][33], sv[32][33];
    const int t  = threadIdx.x;
    const int r0 = blockIdx.x * 32;

    const float wq = ipw[0], wk = ipw[1], wv = ipw[2];
    const float bq = ipb[0], bk = ipb[1], bv = ipb[2];

    const int f = r0 * NN + t * 4;     // coalesced: 4 consecutive n of one row
    const float4 q4 = *reinterpret_cast<const float4*>(q_in + f);
    const float4 k4 = *reinterpret_cast<const float4*>(k_in + f);
    const float4 v4 = *reinterpret_cast<const float4*>(v_in + f);

    const int row = t >> 3, nc = (t & 7) * 4;
    sa[row][nc + 0] = fmaf(q4.x, wq, bq) * LOG2E;
    sa[row][nc + 1] = fmaf(q4.y, wq, bq) * LOG2E;
    sa[row][nc + 2] = fmaf(q4.z, wq, bq) * LOG2E;
    sa[row][nc + 3] = fmaf(q4.w, wq, bq) * LOG2E;
    sk[row][nc + 0] = fmaf(k4.x, wk, bk);
    sk[row][nc + 1] = fmaf(k4.y, wk, bk);
    sk[row][nc + 2] = fmaf(k4.z, wk, bk);
    sk[row][nc + 3] = fmaf(k4.w, wk, bk);
    sv[row][nc + 0] = fmaf(v4.x, wv, bv);
    sv[row][nc + 1] = fmaf(v4.y, wv, bv);
    sv[row][nc + 2] = fmaf(v4.z, wv, bv);
    sv[row][nc + 3] = fmaf(v4.w, wv, bv);
    __syncthreads();

    float* __restrict__ A = ws;
    float* __restrict__ K = ws + (size_t)LL * NN;
    float* __restrict__ V = ws + (size_t)2 * LL * NN;
    const int n = t >> 3, j0 = (t & 7) * 4;  // coalesced: 4 consecutive rows

    float4 o;
    o.x = sa[j0 + 0][n]; o.y = sa[j0 + 1][n]; o.z = sa[j0 + 2][n]; o.w = sa[j0 + 3][n];
    *reinterpret_cast<float4*>(A + (size_t)n * LL + r0 + j0) = o;
    o.x = sk[j0 + 0][n]; o.y = sk[j0 + 1][n]; o.z = sk[j0 + 2][n]; o.w = sk[j0 + 3][n];
    *reinterpret_cast<float4*>(K + (size_t)n * LL + r0 + j0) = o;
    o.x = sv[j0 + 0][n]; o.y = sv[j0 + 1][n]; o.z = sv[j0 + 2][n]; o.w = sv[j0 + 3][n];
    *reinterpret_cast<float4*>(V + (size_t)n * LL + r0 + j0) = o;
}

// ---------------- Kernel A: packed rank-1 softmax, coalesced ----------------
// grid = 4096 WGs, 256 threads = 1 row each.
__global__ __launch_bounds__(256) void attn_kernel(
    const float* __restrict__ ws,
    const float* __restrict__ opw, const float* __restrict__ opb,
    float* __restrict__ out)
{
    const int g   = blockIdx.x;
    const int blk = g >> 5;
    const int n   = g & 31;
    const int tid = threadIdx.x;

    const float* __restrict__ A = ws;
    const float* __restrict__ K = ws + (size_t)LL * NN;
    const float* __restrict__ V = ws + (size_t)2 * LL * NN;
    const int base = n * LL + blk * BSZ;

    __shared__ alignas(16) float2 skv[BSZ];   // (k_j, v_j) interleaved

    const float a = A[base + tid];            // coalesced (includes LOG2E)
    skv[tid] = make_float2(K[base + tid], V[base + tid]);  // coalesced
    __syncthreads();

    const v2f a2 = {a, a};
    v2f den_e = {0.f, 0.f}, den_o = {0.f, 0.f};
    v2f num_e = {0.f, 0.f}, num_o = {0.f, 0.f};

    const float4* __restrict__ s4 = (const float4*)skv;  // 128 chunks (k0,v0,k1,v1)

    #pragma unroll 8
    for (int t = 0; t < BSZ / 2; t += 2) {    // all 128 float4 chunks
        const float4 c0 = s4[t];       // uniform ds_read_b128 -> 2 j's
        const float4 c1 = s4[t + 1];
        {
            const v2f arg = a2 * (v2f){c0.x, c0.z};   // v_pk_mul_f32
            v2f p;
            p.x = __builtin_amdgcn_exp2f(arg.x);
            p.y = __builtin_amdgcn_exp2f(arg.y);
            den_e += p;                                // v_pk_add_f32
            num_e = __builtin_elementwise_fma(p, (v2f){c0.y, c0.w}, num_e);
        }
        {
            const v2f arg = a2 * (v2f){c1.x, c1.z};
            v2f p;
            p.x = __builtin_amdgcn_exp2f(arg.x);
            p.y = __builtin_amdgcn_exp2f(arg.y);
            den_o += p;
            num_o = __builtin_elementwise_fma(p, (v2f){c1.y, c1.w}, num_o);
        }
    }

    const v2f dsum = den_e + den_o;
    const v2f nsum = num_e + num_o;
    const float den = dsum.x + dsum.y;
    const float num = nsum.x + nsum.y;
    out[(size_t)(blk * BSZ + tid) * NN + n] = fmaf(num / den, opw[0], opb[0]);
}

extern "C" void kernel_launch(void* const* d_in, const int* in_sizes, int n_in,
                              void* d_out, int out_size, void* d_ws, size_t ws_size,
                              hipStream_t stream) {
    const float* q   = (const float*)d_in[0];
    const float* k   = (const float*)d_in[1];
    const float* v   = (const float*)d_in[2];
    const float* ipw = (const float*)d_in[3];
    const float* ipb = (const float*)d_in[4];
    const float* opw = (const float*)d_in[5];
    const float* opb = (const float*)d_in[6];
    float* out = (float*)d_out;
    float* ws  = (float*)d_ws;   // needs 3*L*N*4 = 12.6 MB

    proj_transpose_kernel<<<dim3(LL / 32), dim3(256), 0, stream>>>(q, k, v, ipw, ipb, ws);
    attn_kernel<<<dim3(NBLK * NN), dim3(256), 0, stream>>>(ws, opw, opb, out);
}

// Round 16
// 33.606 us; speedup vs baseline: 1.8398x; 1.5396x over previous
//
#include <hip/hip_runtime.h>

// L=32768, N=32, E=H=1, BS=256 -> 4096 rank-1 softmax problems:
//   out_i = sum_j 2^(a'_i k_j) v_j / sum_j 2^(a'_i k_j),  a' = (wq q + bq) log2e.
// No max-subtraction (f32-safe, scale-invariant; validated R5-R15).
//
// R16: segmented-Taylor moments. k-range split into 32 equal-width segments
// (R13's verified counting sort, 128 bins -> 4 bins/seg). Per segment s:
//   M_{s,d} = sum_{j in s} (k_j - c_s)^d / d!   and v-weighted version.
// Shared by all 256 rows. Per row i (u = a'_i ln2):
//   den_i = sum_s 2^(a'_i c_s) * Horner_u(Mden_s),  num_i likewise.
// Per row: 32 exps (was 256) + ~64 packed FMA (was ~128 packed VALU).
// |u*dk| <= ~0.66 -> deg-7 tail < 1e-6 rel. All-positive den, no cancellation.
// Deterministic: sorted order + serial per-lane segment scans (no f32 atomics).

#define LL    32768
#define NN    32
#define BSZ   256
#define NBLK  (LL / BSZ)
#define NSEG  32
#define LOG2E 1.4426950408889634f
#define LN2   0.6931471805599453f

typedef float v2f __attribute__((ext_vector_type(2)));

__global__ __launch_bounds__(256) void BlockCrossAttn_kernel(
    const float* __restrict__ q_in, const float* __restrict__ k_in,
    const float* __restrict__ v_in,
    const float* __restrict__ ipw,  const float* __restrict__ ipb,
    const float* __restrict__ opw,  const float* __restrict__ opb,
    float* __restrict__ out)
{
    const int wid  = threadIdx.x >> 6;       // wave 0..3: one problem each
    const int lane = threadIdx.x & 63;
    const int prob = blockIdx.x * 4 + wid;   // 0..4095
    const int blk  = prob >> 5;
    const int n    = prob & 31;

    const float wq = ipw[0], wk = ipw[1], wv = ipw[2];
    const float bq = ipb[0], bk = ipb[1], bv = ipb[2];

    __shared__ alignas(16) float2 skv[4][BSZ];      // sorted (k, v)
    __shared__ alignas(16) float  mom[4][NSEG][16]; // [den d0..7 | num d0..7], /d!
    __shared__ int hist[4][128];

    // ---- gather + project (R11/R13 layout: lane owns rows lane+{0,64,128,192})
    float a[4], kr[4], vr[4];
    #pragma unroll
    for (int r = 0; r < 4; ++r) {
        const int gi = (blk * BSZ + r * 64 + lane) * NN + n;
        a[r]  = fmaf(q_in[gi], wq, bq) * LOG2E;
        kr[r] = fmaf(k_in[gi], wk, bk);
        vr[r] = fmaf(v_in[gi], wv, bv);
    }

    // wave reduce kmin/kmax
    float kmn = fminf(fminf(kr[0], kr[1]), fminf(kr[2], kr[3]));
    float kmx = fmaxf(fmaxf(kr[0], kr[1]), fmaxf(kr[2], kr[3]));
    #pragma unroll
    for (int off = 32; off >= 1; off >>= 1) {
        kmn = fminf(kmn, __shfl_xor(kmn, off));
        kmx = fmaxf(kmx, __shfl_xor(kmx, off));
    }

    // ---- counting sort by 7-bit quantized k (verified R13) ----
    hist[wid][lane]      = 0;
    hist[wid][lane + 64] = 0;
    __syncthreads();

    const float rng  = kmx - kmn;
    const float binv = (rng > 0.f) ? (127.99f / rng) : 0.f;
    int bin[4];
    #pragma unroll
    for (int r = 0; r < 4; ++r) {
        int b = (int)((kr[r] - kmn) * binv);
        bin[r] = (b < 0) ? 0 : ((b > 127) ? 127 : b);
        atomicAdd(&hist[wid][bin[r]], 1);   // per-wave LDS atomics: lane-ordered
    }
    __syncthreads();

    const int c0 = hist[wid][lane];
    const int c1 = hist[wid][lane + 64];
    int i0 = c0, i1 = c1;
    #pragma unroll
    for (int off = 1; off <= 32; off <<= 1) {
        const int t0 = __shfl_up(i0, off);
        const int t1 = __shfl_up(i1, off);
        if (lane >= off) { i0 += t0; i1 += t1; }
    }
    const int tot0 = __shfl(i0, 63);
    hist[wid][lane]      = i0 - c0;          // exclusive bin starts
    hist[wid][lane + 64] = i1 - c1 + tot0;
    __syncthreads();

    #pragma unroll
    for (int r = 0; r < 4; ++r) {
        const int slot = atomicAdd(&hist[wid][bin[r]], 1);
        skv[wid][slot] = make_float2(kr[r], vr[r]);
    }
    __syncthreads();
    // post-scatter: hist[b] = END offset of bin b

    // ---- per-segment moments: lane = (seg, part); serial, deterministic ----
    const float segw = rng * (1.0f / NSEG);
    {
        const int s   = lane & 31;
        const int prt = lane >> 5;           // 0: den (w=1), 1: num (w=v)
        const int beg = (s == 0) ? 0 : hist[wid][4 * s - 1];
        const int end = hist[wid][4 * s + 3];
        const float cs = kmn + (s + 0.5f) * segw;
        float m0=0.f,m1=0.f,m2=0.f,m3=0.f,m4=0.f,m5=0.f,m6=0.f,m7=0.f;
        for (int e = beg; e < end; ++e) {
            const float2 kv = skv[wid][e];
            const float dk = kv.x - cs;
            float p = prt ? kv.y : 1.0f;
            m0 += p; p *= dk;
            m1 += p; p *= dk;
            m2 += p; p *= dk;
            m3 += p; p *= dk;
            m4 += p; p *= dk;
            m5 += p; p *= dk;
            m6 += p; p *= dk;
            m7 += p;
        }
        float* mp = &mom[wid][s][prt * 8];
        mp[0] = m0;
        mp[1] = m1;
        mp[2] = m2 * 0.5f;
        mp[3] = m3 * (1.f / 6.f);
        mp[4] = m4 * (1.f / 24.f);
        mp[5] = m5 * (1.f / 120.f);
        mp[6] = m6 * (1.f / 720.f);
        mp[7] = m7 * (1.f / 5040.f);
    }
    __syncthreads();

    // ---- row loop: 4 rows/lane packed as 2 v2f pairs, 32 segments ----
    const v2f a01 = {a[0], a[1]};
    const v2f a23 = {a[2], a[3]};
    const v2f u01 = {a[0] * LN2, a[1] * LN2};
    const v2f u23 = {a[2] * LN2, a[3] * LN2};

    v2f den01 = {0.f, 0.f}, den23 = {0.f, 0.f};
    v2f num01 = {0.f, 0.f}, num23 = {0.f, 0.f};

    const float4* __restrict__ M4 = (const float4*)mom[wid];  // 4 float4 / seg

    #pragma unroll 4
    for (int s = 0; s < NSEG; ++s) {
        const float4 D0 = M4[s * 4 + 0];   // den moments d0..3 (uniform b128)
        const float4 D1 = M4[s * 4 + 1];   // den moments d4..7
        const float4 N0 = M4[s * 4 + 2];   // num moments d0..3
        const float4 N1 = M4[s * 4 + 3];   // num moments d4..7
        const float cs = kmn + (s + 0.5f) * segw;
        const v2f cs2 = {cs, cs};

        const v2f e01 = a01 * cs2;         // v_pk_mul
        const v2f e23 = a23 * cs2;
        v2f E01, E23;
        E01.x = __builtin_amdgcn_exp2f(e01.x);
        E01.y = __builtin_amdgcn_exp2f(e01.y);
        E23.x = __builtin_amdgcn_exp2f(e23.x);
        E23.y = __builtin_amdgcn_exp2f(e23.y);

        v2f hd01 = {D1.w, D1.w}, hd23 = {D1.w, D1.w};
        hd01 = __builtin_elementwise_fma(hd01, u01, (v2f){D1.z, D1.z});
        hd23 = __builtin_elementwise_fma(hd23, u23, (v2f){D1.z, D1.z});
        hd01 = __builtin_elementwise_fma(hd01, u01, (v2f){D1.y, D1.y});
        hd23 = __builtin_elementwise_fma(hd23, u23, (v2f){D1.y, D1.y});
        hd01 = __builtin_elementwise_fma(hd01, u01, (v2f){D1.x, D1.x});
        hd23 = __builtin_elementwise_fma(hd23, u23, (v2f){D1.x, D1.x});
        hd01 = __builtin_elementwise_fma(hd01, u01, (v2f){D0.w, D0.w});
        hd23 = __builtin_elementwise_fma(hd23, u23, (v2f){D0.w, D0.w});
        hd01 = __builtin_elementwise_fma(hd01, u01, (v2f){D0.z, D0.z});
        hd23 = __builtin_elementwise_fma(hd23, u23, (v2f){D0.z, D0.z});
        hd01 = __builtin_elementwise_fma(hd01, u01, (v2f){D0.y, D0.y});
        hd23 = __builtin_elementwise_fma(hd23, u23, (v2f){D0.y, D0.y});
        hd01 = __builtin_elementwise_fma(hd01, u01, (v2f){D0.x, D0.x});
        hd23 = __builtin_elementwise_fma(hd23, u23, (v2f){D0.x, D0.x});

        v2f hn01 = {N1.w, N1.w}, hn23 = {N1.w, N1.w};
        hn01 = __builtin_elementwise_fma(hn01, u01, (v2f){N1.z, N1.z});
        hn23 = __builtin_elementwise_fma(hn23, u23, (v2f){N1.z, N1.z});
        hn01 = __builtin_elementwise_fma(hn01, u01, (v2f){N1.y, N1.y});
        hn23 = __builtin_elementwise_fma(hn23, u23, (v2f){N1.y, N1.y});
        hn01 = __builtin_elementwise_fma(hn01, u01, (v2f){N1.x, N1.x});
        hn23 = __builtin_elementwise_fma(hn23, u23, (v2f){N1.x, N1.x});
        hn01 = __builtin_elementwise_fma(hn01, u01, (v2f){N0.w, N0.w});
        hn23 = __builtin_elementwise_fma(hn23, u23, (v2f){N0.w, N0.w});
        hn01 = __builtin_elementwise_fma(hn01, u01, (v2f){N0.z, N0.z});
        hn23 = __builtin_elementwise_fma(hn23, u23, (v2f){N0.z, N0.z});
        hn01 = __builtin_elementwise_fma(hn01, u01, (v2f){N0.y, N0.y});
        hn23 = __builtin_elementwise_fma(hn23, u23, (v2f){N0.y, N0.y});
        hn01 = __builtin_elementwise_fma(hn01, u01, (v2f){N0.x, N0.x});
        hn23 = __builtin_elementwise_fma(hn23, u23, (v2f){N0.x, N0.x});

        den01 = __builtin_elementwise_fma(E01, hd01, den01);
        den23 = __builtin_elementwise_fma(E23, hd23, den23);
        num01 = __builtin_elementwise_fma(E01, hn01, num01);
        num23 = __builtin_elementwise_fma(E23, hn23, num23);
    }

    const float wo = opw[0], bo = opb[0];
    const int rbase = blk * BSZ;
    out[(size_t)(rbase +   0 + lane) * NN + n] = fmaf(num01.x / den01.x, wo, bo);
    out[(size_t)(rbase +  64 + lane) * NN + n] = fmaf(num01.y / den01.y, wo, bo);
    out[(size_t)(rbase + 128 + lane) * NN + n] = fmaf(num23.x / den23.x, wo, bo);
    out[(size_t)(rbase + 192 + lane) * NN + n] = fmaf(num23.y / den23.y, wo, bo);
}

extern "C" void kernel_launch(void* const* d_in, const int* in_sizes, int n_in,
                              void* d_out, int out_size, void* d_ws, size_t ws_size,
                              hipStream_t stream) {
    const float* q   = (const float*)d_in[0];
    const float* k   = (const float*)d_in[1];
    const float* v   = (const float*)d_in[2];
    const float* ipw = (const float*)d_in[3];
    const float* ipb = (const float*)d_in[4];
    const float* opw = (const float*)d_in[5];
    const float* opb = (const float*)d_in[6];
    float* out = (float*)d_out;

    dim3 grid(NBLK * NN / 4);   // 1024 WGs x 4 waves; one problem per wave
    dim3 block(256);
    BlockCrossAttn_kernel<<<grid, block, 0, stream>>>(q, k, v, ipw, ipb, opw, opb, out);
}